// Round 3
// baseline (771.860 us; speedup 1.0000x reference)
//
#include <hip/hip_runtime.h>
#include <stdint.h>

#define C 8
#define K 27
#define BLOCK 256
#define WSTRIDE 66               // padded fp32 weight stride per k in LDS (2-way max bank conflict)
#define WSZ (K * C * C)          // 1728 floats per layer
#define ENTRY_CAP (1u << 22)     // 4M entries max (actual ~3.6M)

__device__ __forceinline__ uint32_t pack_bf2(float a, float b) {
    uint32_t ua = __float_as_uint(a);
    uint32_t ub = __float_as_uint(b);
    ua = (ua + 0x7FFFu + ((ua >> 16) & 1u)) >> 16;
    ub = (ub + 0x7FFFu + ((ub >> 16) & 1u)) & 0xFFFF0000u;
    return ua | ub;
}

__global__ __launch_bounds__(BLOCK) void to_bf16_kernel(
    const float4* __restrict__ x, uint4* __restrict__ t, int n)
{
    int i = blockIdx.x * BLOCK + threadIdx.x;
    if (i >= n) return;
    float4 a = x[(size_t)i * 2], b = x[(size_t)i * 2 + 1];
    uint4 o;
    o.x = pack_bf2(a.x, a.y);
    o.y = pack_bf2(a.z, a.w);
    o.z = pack_bf2(b.x, b.y);
    o.w = pack_bf2(b.z, b.w);
    t[i] = o;
}

__global__ void zero_ctr_kernel(uint32_t* ctr) {
    if (threadIdx.x == 0 && blockIdx.x == 0) *ctr = 0;
}

__global__ __launch_bounds__(BLOCK) void build_csr_kernel(
    const int* __restrict__ nbr, uint32_t* __restrict__ off,
    uint32_t* __restrict__ entries, uint32_t* __restrict__ ctr, int n)
{
    int i = blockIdx.x * BLOCK + threadIdx.x;
    if (i >= n) return;
    uint32_t tmp[K];
    int cnt = 0;
#pragma unroll
    for (int k = 0; k < K; ++k) {
        int idx = nbr[(size_t)i * K + k];
        if (idx >= 0) tmp[cnt++] = ((uint32_t)k << 19) | (uint32_t)idx;
    }
    uint32_t base = atomicAdd(ctr, (uint32_t)cnt);
    off[i] = base | ((uint32_t)cnt << 27);
    if (base + (uint32_t)cnt <= ENTRY_CAP)
        for (int j = 0; j < cnt; ++j) entries[base + j] = tmp[j];
}

// CSR conv: only valid taps. xt = bf16 table [n] uint4.
template<int RELU, int OUTBF16>
__global__ __launch_bounds__(BLOCK) void sconv_csr_kernel(
    const uint4* __restrict__ xt, const float* __restrict__ Wl,
    const uint32_t* __restrict__ off, const uint32_t* __restrict__ entries,
    const float* __restrict__ resid, void* __restrict__ yout, int n)
{
    __shared__ float w_lds[K * WSTRIDE];
    for (int t = threadIdx.x; t < WSZ; t += BLOCK) {
        int k = t >> 6, r = t & 63;
        w_lds[k * WSTRIDE + r] = Wl[t];
    }
    __syncthreads();

    int i = blockIdx.x * BLOCK + threadIdx.x;
    if (i >= n) return;

    uint32_t o = off[i];
    uint32_t base = o & 0x7FFFFFFu;
    int cnt = (int)(o >> 27);

    float acc[C];
#pragma unroll
    for (int d = 0; d < C; ++d) acc[d] = 0.f;

    uint32_t e = 0;
    uint4 g = make_uint4(0u, 0u, 0u, 0u);
    if (cnt > 0) {
        e = entries[base];
        g = xt[e & 0x7FFFFu];
    }
    for (int j = 0; j < cnt; ++j) {
        uint32_t e_n = 0;
        uint4 g_n = make_uint4(0u, 0u, 0u, 0u);
        if (j + 1 < cnt) {
            e_n = entries[base + j + 1];
            g_n = xt[e_n & 0x7FFFFu];
        }
        const float* wk = w_lds + (e >> 19) * WSTRIDE;
#pragma unroll
        for (int c = 0; c < C; ++c) {
            uint32_t w32 = (&g.x)[c >> 1];
            float a = (c & 1) ? __uint_as_float(w32 & 0xFFFF0000u)
                              : __uint_as_float(w32 << 16);
#pragma unroll
            for (int d = 0; d < C; ++d) acc[d] += a * wk[c * 8 + d];
        }
        e = e_n;
        g = g_n;
    }

#pragma unroll
    for (int d = 0; d < C; ++d)
        if (RELU) acc[d] = fmaxf(acc[d], 0.f);

    if (OUTBF16) {
        uint4 ov;
        ov.x = pack_bf2(acc[0], acc[1]);
        ov.y = pack_bf2(acc[2], acc[3]);
        ov.z = pack_bf2(acc[4], acc[5]);
        ov.w = pack_bf2(acc[6], acc[7]);
        ((uint4*)yout)[i] = ov;
    } else {
        const float4* r = (const float4*)(resid + (size_t)i * C);
        float4 r0 = r[0], r1 = r[1];
        float4 o0 = make_float4(acc[0] + r0.x, acc[1] + r0.y, acc[2] + r0.z, acc[3] + r0.w);
        float4 o1 = make_float4(acc[4] + r1.x, acc[5] + r1.y, acc[6] + r1.z, acc[7] + r1.w);
        float4* yp = (float4*)((float*)yout + (size_t)i * C);
        yp[0] = o0;
        yp[1] = o1;
    }
}

// Fallback (small ws): dense 27-tap loop, nbr row-major.
template<int RELU, int OUTBF16>
__global__ __launch_bounds__(BLOCK) void sconv_dense_kernel(
    const uint4* __restrict__ xt, const float* __restrict__ Wl,
    const int* __restrict__ nbr, const float* __restrict__ resid,
    void* __restrict__ yout, int n)
{
    __shared__ float w_lds[WSZ];
    for (int t = threadIdx.x; t < WSZ; t += BLOCK) w_lds[t] = Wl[t];
    __syncthreads();
    int i = blockIdx.x * BLOCK + threadIdx.x;
    if (i >= n) return;
    float acc[C];
#pragma unroll
    for (int d = 0; d < C; ++d) acc[d] = 0.f;
#pragma unroll 1
    for (int k = 0; k < K; ++k) {
        int idx = nbr[(size_t)i * K + k];
        uint4 g = (idx >= 0) ? xt[idx] : make_uint4(0u, 0u, 0u, 0u);
        const float4* wk = (const float4*)(w_lds + k * C * C);
#pragma unroll
        for (int c = 0; c < C; ++c) {
            float4 wlo = wk[c * 2], whi = wk[c * 2 + 1];
            uint32_t w32 = (&g.x)[c >> 1];
            float a = (c & 1) ? __uint_as_float(w32 & 0xFFFF0000u)
                              : __uint_as_float(w32 << 16);
            acc[0] += a * wlo.x; acc[1] += a * wlo.y;
            acc[2] += a * wlo.z; acc[3] += a * wlo.w;
            acc[4] += a * whi.x; acc[5] += a * whi.y;
            acc[6] += a * whi.z; acc[7] += a * whi.w;
        }
    }
#pragma unroll
    for (int d = 0; d < C; ++d)
        if (RELU) acc[d] = fmaxf(acc[d], 0.f);
    if (OUTBF16) {
        uint4 ov;
        ov.x = pack_bf2(acc[0], acc[1]);
        ov.y = pack_bf2(acc[2], acc[3]);
        ov.z = pack_bf2(acc[4], acc[5]);
        ov.w = pack_bf2(acc[6], acc[7]);
        ((uint4*)yout)[i] = ov;
    } else {
        const float4* r = (const float4*)(resid + (size_t)i * C);
        float4 r0 = r[0], r1 = r[1];
        float4 o0 = make_float4(acc[0] + r0.x, acc[1] + r0.y, acc[2] + r0.z, acc[3] + r0.w);
        float4 o1 = make_float4(acc[4] + r1.x, acc[5] + r1.y, acc[6] + r1.z, acc[7] + r1.w);
        float4* yp = (float4*)((float*)yout + (size_t)i * C);
        yp[0] = o0;
        yp[1] = o1;
    }
}

extern "C" void kernel_launch(void* const* d_in, const int* in_sizes, int n_in,
                              void* d_out, int out_size, void* d_ws, size_t ws_size,
                              hipStream_t stream) {
    const float* feats0 = (const float*)d_in[0];
    const float* feats1 = (const float*)d_in[1];
    const float* W0     = (const float*)d_in[2];
    const float* W1     = (const float*)d_in[3];
    const int*   nbr0   = (const int*)d_in[4];
    const int*   nbr1   = (const int*)d_in[5];
    float* out = (float*)d_out;

    const int n = in_sizes[0] / C;  // 500000

    // ws layout
    char* ws = (char*)d_ws;
    uint4* bufA = (uint4*)ws;                                // n*16 B
    uint4* bufB = (uint4*)(ws + (size_t)n * 16);             // n*16 B
    uint32_t* offs = (uint32_t*)(ws + (size_t)n * 32);       // n*4 B
    uint32_t* ctr  = (uint32_t*)(ws + (size_t)n * 36);       // 4 B (padded to 64)
    uint32_t* entries = (uint32_t*)(ws + (size_t)n * 36 + 64);
    const size_t need = (size_t)n * 36 + 64 + (size_t)ENTRY_CAP * 4;
    const bool use_csr = ws_size >= need;

    dim3 blk(BLOCK);
    int grid1 = (n + BLOCK - 1) / BLOCK;

    for (int g = 0; g < 2; ++g) {
        const float* x0  = g ? feats1 : feats0;
        const float* Wg  = g ? W1 : W0;
        const int*   nbr = g ? nbr1 : nbr0;
        float* og = out + (size_t)g * n * C;

        to_bf16_kernel<<<grid1, blk, 0, stream>>>((const float4*)x0, bufA, n);
        if (use_csr) {
            zero_ctr_kernel<<<1, 64, 0, stream>>>(ctr);
            build_csr_kernel<<<grid1, blk, 0, stream>>>(nbr, offs, entries, ctr, n);
            sconv_csr_kernel<1, 1><<<grid1, blk, 0, stream>>>(bufA, Wg,           offs, entries, nullptr, bufB, n);
            sconv_csr_kernel<1, 1><<<grid1, blk, 0, stream>>>(bufB, Wg + WSZ,     offs, entries, nullptr, bufA, n);
            sconv_csr_kernel<0, 0><<<grid1, blk, 0, stream>>>(bufA, Wg + 2 * WSZ, offs, entries, x0,      og,   n);
        } else {
            sconv_dense_kernel<1, 1><<<grid1, blk, 0, stream>>>(bufA, Wg,           nbr, nullptr, bufB, n);
            sconv_dense_kernel<1, 1><<<grid1, blk, 0, stream>>>(bufB, Wg + WSZ,     nbr, nullptr, bufA, n);
            sconv_dense_kernel<0, 0><<<grid1, blk, 0, stream>>>(bufA, Wg + 2 * WSZ, nbr, x0,      og,   n);
        }
    }
}

// Round 4
// 751.166 us; speedup vs baseline: 1.0275x; 1.0275x over previous
//
#include <hip/hip_runtime.h>
#include <stdint.h>

#define C 8
#define K 27
#define BLOCK 256
#define WSZ (K * C * C)      // 1728 floats per layer
#define ECAP 3900000u        // entries capacity (expected ~3.53M)

__device__ __forceinline__ uint32_t pack_bf2(float a, float b) {
    uint32_t ua = __float_as_uint(a);
    uint32_t ub = __float_as_uint(b);
    ua = (ua + 0x7FFFu + ((ua >> 16) & 1u)) >> 16;
    ub = (ub + 0x7FFFu + ((ub >> 16) & 1u)) & 0xFFFF0000u;
    return ua | ub;  // lo = bf16(a), hi = bf16(b)
}

__global__ __launch_bounds__(BLOCK) void to_bf16_kernel(
    const float4* __restrict__ x, uint4* __restrict__ t, int n)
{
    int i = blockIdx.x * BLOCK + threadIdx.x;
    if (i >= n) return;
    float4 a = x[(size_t)i * 2], b = x[(size_t)i * 2 + 1];
    uint4 o;
    o.x = pack_bf2(a.x, a.y);
    o.y = pack_bf2(a.z, a.w);
    o.z = pack_bf2(b.x, b.y);
    o.w = pack_bf2(b.z, b.w);
    t[i] = o;
}

__global__ void zero_ctr_kernel(uint32_t* ctr) {
    if (threadIdx.x == 0 && blockIdx.x == 0) *ctr = 0;
}

// mask(27 bits) + base offset + packed idx stream. v[] is statically indexed
// in fully-unrolled loops -> stays in registers (no scratch; R3 lesson).
__global__ __launch_bounds__(BLOCK) void build_kernel(
    const int* __restrict__ nbr, uint32_t* __restrict__ mask_arr,
    uint32_t* __restrict__ off_arr, uint32_t* __restrict__ entries,
    uint32_t* __restrict__ ctr, int n)
{
    int i = blockIdx.x * BLOCK + threadIdx.x;
    if (i >= n) return;
    int v[K];
    uint32_t mask = 0;
#pragma unroll
    for (int k = 0; k < K; ++k) {
        v[k] = nbr[(size_t)i * K + k];
        mask |= (uint32_t)(v[k] >= 0) << k;
    }
    int cnt = __popc(mask);
    uint32_t base = atomicAdd(ctr, (uint32_t)cnt);
    mask_arr[i] = mask;
    off_arr[i] = base;
    if (base + (uint32_t)cnt <= ECAP) {
        uint32_t p = base;
#pragma unroll
        for (int k = 0; k < K; ++k)
            if (v[k] >= 0) entries[p++] = (uint32_t)v[k];
    }
}

// Uniform-k loop: weight reads are wave-uniform LDS broadcasts (free).
// Per-lane cursor into the packed entry stream replaces the 108 B/voxel nbr row.
template<int RELU, int OUTBF16>
__global__ __launch_bounds__(BLOCK) void sconv_kernel(
    const uint4* __restrict__ xt, const float* __restrict__ Wl,
    const uint32_t* __restrict__ mask_arr, const uint32_t* __restrict__ off_arr,
    const uint32_t* __restrict__ entries, const float* __restrict__ resid,
    void* __restrict__ yout, int n)
{
    __shared__ float w_lds[WSZ];
    for (int t = threadIdx.x; t < WSZ; t += BLOCK) w_lds[t] = Wl[t];
    __syncthreads();

    int i = blockIdx.x * BLOCK + threadIdx.x;
    if (i >= n) return;

    uint32_t mask = mask_arr[i];
    uint32_t p = off_arr[i];

    float acc[C];
#pragma unroll
    for (int d = 0; d < C; ++d) acc[d] = 0.f;

#pragma unroll 1
    for (int k = 0; k < K; ++k) {
        uint4 g = make_uint4(0u, 0u, 0u, 0u);
        if ((mask >> k) & 1u) {
            uint32_t idx = entries[p++];
            g = xt[idx];
        }
        const float4* wk = (const float4*)(w_lds + k * C * C);
#pragma unroll
        for (int c = 0; c < C; ++c) {
            float4 wlo = wk[c * 2], whi = wk[c * 2 + 1];
            uint32_t w32 = (&g.x)[c >> 1];
            float a = (c & 1) ? __uint_as_float(w32 & 0xFFFF0000u)
                              : __uint_as_float(w32 << 16);
            acc[0] += a * wlo.x; acc[1] += a * wlo.y;
            acc[2] += a * wlo.z; acc[3] += a * wlo.w;
            acc[4] += a * whi.x; acc[5] += a * whi.y;
            acc[6] += a * whi.z; acc[7] += a * whi.w;
        }
    }

#pragma unroll
    for (int d = 0; d < C; ++d)
        if (RELU) acc[d] = fmaxf(acc[d], 0.f);

    if (OUTBF16) {
        uint4 ov;
        ov.x = pack_bf2(acc[0], acc[1]);
        ov.y = pack_bf2(acc[2], acc[3]);
        ov.z = pack_bf2(acc[4], acc[5]);
        ov.w = pack_bf2(acc[6], acc[7]);
        ((uint4*)yout)[i] = ov;
    } else {
        const float4* r = (const float4*)(resid + (size_t)i * C);
        float4 r0 = r[0], r1 = r[1];
        float4 o0 = make_float4(acc[0] + r0.x, acc[1] + r0.y, acc[2] + r0.z, acc[3] + r0.w);
        float4 o1 = make_float4(acc[4] + r1.x, acc[5] + r1.y, acc[6] + r1.z, acc[7] + r1.w);
        float4* yp = (float4*)((float*)yout + (size_t)i * C);
        yp[0] = o0;
        yp[1] = o1;
    }
}

// Fallback (small ws): R2 dense path, row-major nbr.
template<int RELU, int OUTBF16>
__global__ __launch_bounds__(BLOCK) void sconv_dense_kernel(
    const uint4* __restrict__ xt, const float* __restrict__ Wl,
    const int* __restrict__ nbr, const float* __restrict__ resid,
    void* __restrict__ yout, int n)
{
    __shared__ float w_lds[WSZ];
    for (int t = threadIdx.x; t < WSZ; t += BLOCK) w_lds[t] = Wl[t];
    __syncthreads();
    int i = blockIdx.x * BLOCK + threadIdx.x;
    if (i >= n) return;
    float acc[C];
#pragma unroll
    for (int d = 0; d < C; ++d) acc[d] = 0.f;
#pragma unroll 1
    for (int k = 0; k < K; ++k) {
        int idx = nbr[(size_t)i * K + k];
        uint4 g = (idx >= 0) ? xt[idx] : make_uint4(0u, 0u, 0u, 0u);
        const float4* wk = (const float4*)(w_lds + k * C * C);
#pragma unroll
        for (int c = 0; c < C; ++c) {
            float4 wlo = wk[c * 2], whi = wk[c * 2 + 1];
            uint32_t w32 = (&g.x)[c >> 1];
            float a = (c & 1) ? __uint_as_float(w32 & 0xFFFF0000u)
                              : __uint_as_float(w32 << 16);
            acc[0] += a * wlo.x; acc[1] += a * wlo.y;
            acc[2] += a * wlo.z; acc[3] += a * wlo.w;
            acc[4] += a * whi.x; acc[5] += a * whi.y;
            acc[6] += a * whi.z; acc[7] += a * whi.w;
        }
    }
#pragma unroll
    for (int d = 0; d < C; ++d)
        if (RELU) acc[d] = fmaxf(acc[d], 0.f);
    if (OUTBF16) {
        uint4 ov;
        ov.x = pack_bf2(acc[0], acc[1]);
        ov.y = pack_bf2(acc[2], acc[3]);
        ov.z = pack_bf2(acc[4], acc[5]);
        ov.w = pack_bf2(acc[6], acc[7]);
        ((uint4*)yout)[i] = ov;
    } else {
        const float4* r = (const float4*)(resid + (size_t)i * C);
        float4 r0 = r[0], r1 = r[1];
        float4 o0 = make_float4(acc[0] + r0.x, acc[1] + r0.y, acc[2] + r0.z, acc[3] + r0.w);
        float4 o1 = make_float4(acc[4] + r1.x, acc[5] + r1.y, acc[6] + r1.z, acc[7] + r1.w);
        float4* yp = (float4*)((float*)yout + (size_t)i * C);
        yp[0] = o0;
        yp[1] = o1;
    }
}

extern "C" void kernel_launch(void* const* d_in, const int* in_sizes, int n_in,
                              void* d_out, int out_size, void* d_ws, size_t ws_size,
                              hipStream_t stream) {
    const float* feats0 = (const float*)d_in[0];
    const float* feats1 = (const float*)d_in[1];
    const float* W0     = (const float*)d_in[2];
    const float* W1     = (const float*)d_in[3];
    const int*   nbr0   = (const int*)d_in[4];
    const int*   nbr1   = (const int*)d_in[5];
    float* out = (float*)d_out;

    const int n = in_sizes[0] / C;  // 500000

    // ws layout (per-grid, reused sequentially):
    char* ws = (char*)d_ws;
    uint4*    xt       = (uint4*)ws;                          // n*16 B bf16 table
    uint32_t* mask_arr = (uint32_t*)(ws + (size_t)n * 16);    // n*4
    uint32_t* off_arr  = (uint32_t*)(ws + (size_t)n * 20);    // n*4
    uint32_t* ctr      = (uint32_t*)(ws + (size_t)n * 24);    // 64 B pad
    uint32_t* entries  = (uint32_t*)(ws + (size_t)n * 24 + 64);
    const size_t need_csr = (size_t)n * 24 + 64 + (size_t)ECAP * 4 + (size_t)K * 16;
    const bool use_csr = ws_size >= need_csr;

    dim3 blk(BLOCK);
    int grid1 = (n + BLOCK - 1) / BLOCK;

    for (int g = 0; g < 2; ++g) {
        const float* x0  = g ? feats1 : feats0;
        const float* Wg  = g ? W1 : W0;
        const int*   nbr = g ? nbr1 : nbr0;
        float* og = out + (size_t)g * n * C;
        uint4* T1 = (uint4*)og;  // lo 8 MB of this grid's out region, bf16 table

        to_bf16_kernel<<<grid1, blk, 0, stream>>>((const float4*)x0, xt, n);
        if (use_csr) {
            zero_ctr_kernel<<<1, 64, 0, stream>>>(ctr);
            build_kernel<<<grid1, blk, 0, stream>>>(nbr, mask_arr, off_arr, entries, ctr, n);
            // L1: xt -> T1 (bf16, relu)
            sconv_kernel<1, 1><<<grid1, blk, 0, stream>>>(xt, Wg, mask_arr, off_arr, entries, nullptr, T1, n);
            // L2: T1 -> xt (bf16, relu; xt dead as input after L1)
            sconv_kernel<1, 1><<<grid1, blk, 0, stream>>>(T1, Wg + WSZ, mask_arr, off_arr, entries, nullptr, xt, n);
            // L3: xt -> og fp32 + residual x0 (T1 dead)
            sconv_kernel<0, 0><<<grid1, blk, 0, stream>>>(xt, Wg + 2 * WSZ, mask_arr, off_arr, entries, x0, og, n);
        } else {
            sconv_dense_kernel<1, 1><<<grid1, blk, 0, stream>>>(xt, Wg, nbr, nullptr, T1, n);
            sconv_dense_kernel<1, 1><<<grid1, blk, 0, stream>>>(T1, Wg + WSZ, nbr, nullptr, xt, n);
            sconv_dense_kernel<0, 0><<<grid1, blk, 0, stream>>>(xt, Wg + 2 * WSZ, nbr, x0, og, n);
        }
    }
}

// Round 5
// 615.905 us; speedup vs baseline: 1.2532x; 1.2196x over previous
//
#include <hip/hip_runtime.h>
#include <stdint.h>

#define C 8
#define K 27
#define BLOCK 256
#define WSZ (K * C * C)      // 1728 floats per layer
#define ECAP 3900000u        // entries capacity (expected ~3.53M)

__device__ __forceinline__ uint32_t pack_bf2(float a, float b) {
    uint32_t ua = __float_as_uint(a);
    uint32_t ub = __float_as_uint(b);
    ua = (ua + 0x7FFFu + ((ua >> 16) & 1u)) >> 16;
    ub = (ub + 0x7FFFu + ((ub >> 16) & 1u)) & 0xFFFF0000u;
    return ua | ub;  // lo = bf16(a), hi = bf16(b)
}

__global__ __launch_bounds__(BLOCK) void to_bf16_kernel(
    const float4* __restrict__ x, uint4* __restrict__ t, int n)
{
    int i = blockIdx.x * BLOCK + threadIdx.x;
    if (i >= n) return;
    float4 a = x[(size_t)i * 2], b = x[(size_t)i * 2 + 1];
    uint4 o;
    o.x = pack_bf2(a.x, a.y);
    o.y = pack_bf2(a.z, a.w);
    o.z = pack_bf2(b.x, b.y);
    o.w = pack_bf2(b.z, b.w);
    t[i] = o;
}

__global__ void zero_ctr_kernel(uint32_t* ctr) {
    if (threadIdx.x == 0 && blockIdx.x == 0) *ctr = 0;
}

// Block-scan compaction: ONE atomic per block (R4 lesson: 500k same-address
// atomics = 102us serialization). Entries stay voxel-contiguous within a
// block -> conv-side entry reads coalesce.
__global__ __launch_bounds__(BLOCK) void build_kernel(
    const int* __restrict__ nbr, uint2* __restrict__ moff,
    uint32_t* __restrict__ entries, uint32_t* __restrict__ ctr, int n)
{
    __shared__ uint32_t sc[BLOCK];
    __shared__ uint32_t sbase;
    int i = blockIdx.x * BLOCK + threadIdx.x;

    int v[K];
    uint32_t mask = 0;
    if (i < n) {
#pragma unroll
        for (int k = 0; k < K; ++k) {
            v[k] = nbr[(size_t)i * K + k];
            mask |= (uint32_t)(v[k] >= 0) << k;
        }
    }
    uint32_t cnt = __popc(mask);
    sc[threadIdx.x] = cnt;
    __syncthreads();
    // Hillis-Steele inclusive scan over BLOCK counts
    for (int s = 1; s < BLOCK; s <<= 1) {
        uint32_t add = (threadIdx.x >= (uint32_t)s) ? sc[threadIdx.x - s] : 0u;
        __syncthreads();
        sc[threadIdx.x] += add;
        __syncthreads();
    }
    if (threadIdx.x == BLOCK - 1) sbase = atomicAdd(ctr, sc[BLOCK - 1]);
    __syncthreads();
    if (i >= n) return;

    uint32_t base = sbase + sc[threadIdx.x] - cnt;  // exclusive prefix
    moff[i] = make_uint2(mask, base);
    if (base + cnt <= ECAP) {
        uint32_t q = base;
#pragma unroll
        for (int k = 0; k < K; ++k)
            if (v[k] >= 0) entries[q++] = (uint32_t)v[k];
    }
}

// Uniform-k loop (weights = free wave-uniform LDS broadcast), per-lane
// cursor into the packed entry stream.
template<int RELU, int OUTBF16>
__global__ __launch_bounds__(BLOCK) void sconv_kernel(
    const uint4* __restrict__ xt, const float* __restrict__ Wl,
    const uint2* __restrict__ moff, const uint32_t* __restrict__ entries,
    const float* __restrict__ resid, void* __restrict__ yout, int n)
{
    __shared__ float w_lds[WSZ];
    for (int t = threadIdx.x; t < WSZ; t += BLOCK) w_lds[t] = Wl[t];
    __syncthreads();

    int i = blockIdx.x * BLOCK + threadIdx.x;
    if (i >= n) return;

    uint2 mo = moff[i];
    uint32_t mask = mo.x;
    uint32_t p = mo.y;

    float acc[C];
#pragma unroll
    for (int d = 0; d < C; ++d) acc[d] = 0.f;

#pragma unroll 1
    for (int k = 0; k < K; ++k) {
        uint4 g = make_uint4(0u, 0u, 0u, 0u);
        if ((mask >> k) & 1u) {
            uint32_t idx = entries[p++];
            g = xt[idx];
        }
        const float4* wk = (const float4*)(w_lds + k * C * C);
#pragma unroll
        for (int c = 0; c < C; ++c) {
            float4 wlo = wk[c * 2], whi = wk[c * 2 + 1];
            uint32_t w32 = (&g.x)[c >> 1];
            float a = (c & 1) ? __uint_as_float(w32 & 0xFFFF0000u)
                              : __uint_as_float(w32 << 16);
            acc[0] += a * wlo.x; acc[1] += a * wlo.y;
            acc[2] += a * wlo.z; acc[3] += a * wlo.w;
            acc[4] += a * whi.x; acc[5] += a * whi.y;
            acc[6] += a * whi.z; acc[7] += a * whi.w;
        }
    }

#pragma unroll
    for (int d = 0; d < C; ++d)
        if (RELU) acc[d] = fmaxf(acc[d], 0.f);

    if (OUTBF16) {
        uint4 ov;
        ov.x = pack_bf2(acc[0], acc[1]);
        ov.y = pack_bf2(acc[2], acc[3]);
        ov.z = pack_bf2(acc[4], acc[5]);
        ov.w = pack_bf2(acc[6], acc[7]);
        ((uint4*)yout)[i] = ov;
    } else {
        const float4* r = (const float4*)(resid + (size_t)i * C);
        float4 r0 = r[0], r1 = r[1];
        float4 o0 = make_float4(acc[0] + r0.x, acc[1] + r0.y, acc[2] + r0.z, acc[3] + r0.w);
        float4 o1 = make_float4(acc[4] + r1.x, acc[5] + r1.y, acc[6] + r1.z, acc[7] + r1.w);
        float4* yp = (float4*)((float*)yout + (size_t)i * C);
        yp[0] = o0;
        yp[1] = o1;
    }
}

// Fallback (small ws): dense path, row-major nbr.
template<int RELU, int OUTBF16>
__global__ __launch_bounds__(BLOCK) void sconv_dense_kernel(
    const uint4* __restrict__ xt, const float* __restrict__ Wl,
    const int* __restrict__ nbr, const float* __restrict__ resid,
    void* __restrict__ yout, int n)
{
    __shared__ float w_lds[WSZ];
    for (int t = threadIdx.x; t < WSZ; t += BLOCK) w_lds[t] = Wl[t];
    __syncthreads();
    int i = blockIdx.x * BLOCK + threadIdx.x;
    if (i >= n) return;
    float acc[C];
#pragma unroll
    for (int d = 0; d < C; ++d) acc[d] = 0.f;
#pragma unroll 1
    for (int k = 0; k < K; ++k) {
        int idx = nbr[(size_t)i * K + k];
        uint4 g = (idx >= 0) ? xt[idx] : make_uint4(0u, 0u, 0u, 0u);
        const float4* wk = (const float4*)(w_lds + k * C * C);
#pragma unroll
        for (int c = 0; c < C; ++c) {
            float4 wlo = wk[c * 2], whi = wk[c * 2 + 1];
            uint32_t w32 = (&g.x)[c >> 1];
            float a = (c & 1) ? __uint_as_float(w32 & 0xFFFF0000u)
                              : __uint_as_float(w32 << 16);
            acc[0] += a * wlo.x; acc[1] += a * wlo.y;
            acc[2] += a * wlo.z; acc[3] += a * wlo.w;
            acc[4] += a * whi.x; acc[5] += a * whi.y;
            acc[6] += a * whi.z; acc[7] += a * whi.w;
        }
    }
#pragma unroll
    for (int d = 0; d < C; ++d)
        if (RELU) acc[d] = fmaxf(acc[d], 0.f);
    if (OUTBF16) {
        uint4 ov;
        ov.x = pack_bf2(acc[0], acc[1]);
        ov.y = pack_bf2(acc[2], acc[3]);
        ov.z = pack_bf2(acc[4], acc[5]);
        ov.w = pack_bf2(acc[6], acc[7]);
        ((uint4*)yout)[i] = ov;
    } else {
        const float4* r = (const float4*)(resid + (size_t)i * C);
        float4 r0 = r[0], r1 = r[1];
        float4 o0 = make_float4(acc[0] + r0.x, acc[1] + r0.y, acc[2] + r0.z, acc[3] + r0.w);
        float4 o1 = make_float4(acc[4] + r1.x, acc[5] + r1.y, acc[6] + r1.z, acc[7] + r1.w);
        float4* yp = (float4*)((float*)yout + (size_t)i * C);
        yp[0] = o0;
        yp[1] = o1;
    }
}

extern "C" void kernel_launch(void* const* d_in, const int* in_sizes, int n_in,
                              void* d_out, int out_size, void* d_ws, size_t ws_size,
                              hipStream_t stream) {
    const float* feats0 = (const float*)d_in[0];
    const float* feats1 = (const float*)d_in[1];
    const float* W0     = (const float*)d_in[2];
    const float* W1     = (const float*)d_in[3];
    const int*   nbr0   = (const int*)d_in[4];
    const int*   nbr1   = (const int*)d_in[5];
    float* out = (float*)d_out;

    const int n = in_sizes[0] / C;  // 500000

    // ws layout (per-grid, reused sequentially):
    char* ws = (char*)d_ws;
    uint4*    xt      = (uint4*)ws;                          // n*16 B bf16 table
    uint2*    moff    = (uint2*)(ws + (size_t)n * 16);       // n*8 B (mask, off)
    uint32_t* ctr     = (uint32_t*)(ws + (size_t)n * 24);    // 64 B pad
    uint32_t* entries = (uint32_t*)(ws + (size_t)n * 24 + 64);
    const size_t need_csr = (size_t)n * 24 + 64 + (size_t)ECAP * 4;
    const bool use_csr = ws_size >= need_csr;

    dim3 blk(BLOCK);
    int grid1 = (n + BLOCK - 1) / BLOCK;

    for (int g = 0; g < 2; ++g) {
        const float* x0  = g ? feats1 : feats0;
        const float* Wg  = g ? W1 : W0;
        const int*   nbr = g ? nbr1 : nbr0;
        float* og = out + (size_t)g * n * C;
        uint4* T1 = (uint4*)og;  // lo 8 MB of this grid's out region, bf16 table

        to_bf16_kernel<<<grid1, blk, 0, stream>>>((const float4*)x0, xt, n);
        if (use_csr) {
            zero_ctr_kernel<<<1, 64, 0, stream>>>(ctr);
            build_kernel<<<grid1, blk, 0, stream>>>(nbr, moff, entries, ctr, n);
            // L1: xt -> T1 (bf16, relu)
            sconv_kernel<1, 1><<<grid1, blk, 0, stream>>>(xt, Wg, moff, entries, nullptr, T1, n);
            // L2: T1 -> xt (bf16, relu; xt dead as input after L1)
            sconv_kernel<1, 1><<<grid1, blk, 0, stream>>>(T1, Wg + WSZ, moff, entries, nullptr, xt, n);
            // L3: xt -> og fp32 + residual x0 (T1 dead)
            sconv_kernel<0, 0><<<grid1, blk, 0, stream>>>(xt, Wg + 2 * WSZ, moff, entries, x0, og, n);
        } else {
            sconv_dense_kernel<1, 1><<<grid1, blk, 0, stream>>>(xt, Wg, nbr, nullptr, T1, n);
            sconv_dense_kernel<1, 1><<<grid1, blk, 0, stream>>>(T1, Wg + WSZ, nbr, nullptr, xt, n);
            sconv_dense_kernel<0, 0><<<grid1, blk, 0, stream>>>(xt, Wg + 2 * WSZ, nbr, x0, og, n);
        }
    }
}